// Round 4
// baseline (652.962 us; speedup 1.0000x reference)
//
#include <hip/hip_runtime.h>

// StackMemory fully-fused kernel for MI355X (gfx950).
// B=4, S=2048, H=1024, NH=16, SLOTS=16, SD=32, HD=64. 8192 tokens.
//
// Single main kernel: one wave per (token, head); one 256-thread block = 4
// waves = 4 heads of ONE token (hid row staged once in 4 KB LDS). Action
// logits (3 per head, 1024-dot each, WaT L2-resident) and the k projection
// (32 x 64-dot) are computed in-register with xor-butterflies -- no stash,
// no second kernel, no extra HBM round trip.
//
// Lane layout for the stack phase: lane l <-> float4 (slot = l>>3, q = l&7).
// 1 KB fully-coalesced global loads/stores; slot shift via lane shuffles;
// gate/softmax/mem-reduce via xor butterflies. After the mem butterfly every
// lane holds its quarter's full sum, so the Wu epilogue uses 8 broadcast
// shuffles -- no LDS round trip, ONE barrier in the whole kernel, 4 KB LDS.
//
// XCD swizzle: sb = (raw>>3) + 4096*(raw&7) puts the 4 blocks of a token on
// the same XCD (blockIdx % 8 = XCD heuristic) so the shared hid row is an
// L2 hit, and gives each XCD a contiguous token range.
//
// Outputs concatenated flat: out [8192*1024] | new_stack [8192*8192] | new_mask [8192*256]

constexpr long long OUT_STACK_OFF = 8388608LL;     // 4*2048*1024
constexpr long long OUT_MASK_OFF  = 75497472LL;    // + 4*2048*16*16*32

__global__ void transpose_wa(const float* __restrict__ Wa, float* __restrict__ WaT) {
    int o = blockIdx.x * 256 + threadIdx.x;        // 48*1024 elements
    if (o < 48 * 1024) {
        int j = o >> 10, i = o & 1023;
        WaT[o] = Wa[i * 48 + j];
    }
}

__device__ __forceinline__ float dot4(float4 a, float4 b) {
    return a.x * b.x + a.y * b.y + a.z * b.z + a.w * b.w;
}

__device__ __forceinline__ float4 shfl4(float4 v, int src) {
    return make_float4(__shfl(v.x, src), __shfl(v.y, src),
                       __shfl(v.z, src), __shfl(v.w, src));
}

__device__ __forceinline__ float4 sel4(bool c, float4 a, float4 b) {
    return make_float4(c ? a.x : b.x, c ? a.y : b.y, c ? a.z : b.z, c ? a.w : b.w);
}

__global__ __launch_bounds__(256, 4)
void stack_main(const float* __restrict__ hid,
                const float* __restrict__ stack,
                const float* __restrict__ mask,
                const float* __restrict__ WaT,   // [48][1024]
                const float* __restrict__ ba,    // [48]
                const float* __restrict__ Wd,    // [64][32]
                const float* __restrict__ bd,    // [32]
                const float* __restrict__ Wg,    // [32]
                const float* __restrict__ bgp,   // [1]
                const float* __restrict__ Wu,    // [32][64]
                const float* __restrict__ bu,    // [64]
                const float* __restrict__ resw,  // [1]
                float* __restrict__ out)
{
    __shared__ __align__(16) float sh_hid[1024];

    const int t = threadIdx.x, wv = t >> 6, l = t & 63;
    // XCD-swizzled block id: 4 blocks of one token -> same XCD, contiguous tokens per XCD
    const int raw = blockIdx.x;
    const int sb  = (raw >> 3) + ((raw & 7) << 12);   // 32768 = 8 * 4096
    const int tok = sb >> 2;
    const int nh  = ((sb & 3) << 2) + wv;

    // ---- stage this token's hidden row (4 KB, one coalesced float4/thread) ----
    const float4* hid4g = (const float4*)(hid + (size_t)tok * 1024);
    ((float4*)sh_hid)[t] = hid4g[t];
    __syncthreads();

    // ---- action logits for head nh: 3 x 1024-dot, lanes cover the row ----
    float4 hreg[4];
    #pragma unroll
    for (int m = 0; m < 4; ++m) hreg[m] = ((const float4*)sh_hid)[m * 64 + l];
    const float4* waT4 = (const float4*)WaT;
    float lac[3];
    #pragma unroll
    for (int a = 0; a < 3; ++a) {
        int j = nh * 3 + a;
        float acc = 0.f;
        #pragma unroll
        for (int m = 0; m < 4; ++m)
            acc += dot4(hreg[m], waT4[j * 256 + m * 64 + l]);   // 1 KB coalesced, L2-hot
        #pragma unroll
        for (int off = 1; off <= 32; off <<= 1) acc += __shfl_xor(acc, off);
        lac[a] = (acc + ba[j]) * 0.125f;                        // /sqrt(64)
    }
    float mx = fmaxf(lac[0], fmaxf(lac[1], lac[2]));
    float e0 = __expf(lac[0] - mx), e1 = __expf(lac[1] - mx), e2 = __expf(lac[2] - mx);
    float ainv = 1.f / (e0 + e1 + e2);
    float ap = e0 * ainv, apop = e1 * ainv, an = e2 * ainv;

    // ---- k projection: lane -> dim d = l&31, half h = l>>5 (32 MACs each) ----
    const int d = l & 31, hh = l >> 5;
    const float* hrow = sh_hid + nh * 64 + hh * 32;             // LDS broadcast reads
    float kacc = 0.f;
    #pragma unroll
    for (int i = 0; i < 32; ++i)
        kacc += hrow[i] * Wd[(hh * 32 + i) * 32 + d];           // coalesced 128 B, L1-hot
    kacc += __shfl_xor(kacc, 32);
    kacc += bd[d];
    // redistribute: lane l needs k[(l&7)*4 + c] (sources in lanes 0..31)
    float4 kv;
    kv.x = __shfl(kacc, ((l & 7) << 2) + 0);
    kv.y = __shfl(kacc, ((l & 7) << 2) + 1);
    kv.z = __shfl(kacc, ((l & 7) << 2) + 2);
    kv.w = __shfl(kacc, ((l & 7) << 2) + 3);

    // ---- stack slice: lane l holds float4 (slot = l>>3, quarter = l&7) ----
    const float4* stk4 = (const float4*)stack + (size_t)tok * 2048 + nh * 128;
    float4 A  = stk4[l];           // slots 0..7   (1 KB coalesced)
    float4 Bv = stk4[64 + l];      // slots 8..15
    const float* mrow_g = mask + (size_t)tok * 256 + nh * 16;
    float mA = mrow_g[l >> 3];
    float mB = mrow_g[8 + (l >> 3)];
    float4 wg = *(const float4*)(Wg + (l & 7) * 4);

    // neighbor rows: slot stride = 8 lanes (unconditional shuffles = convergent)
    float4 Am  = shfl4(A,  l - 8);   // slot-1 within A
    float4 Apl = shfl4(A,  l + 8);   // slot+1 within A
    float4 BfA = shfl4(A,  l + 56);  // slot7 -> prev of slot8 (lanes l<8)
    float4 AfB = shfl4(Bv, l - 56);  // slot8 -> next of slot7 (lanes l>=56)
    float4 Bm  = shfl4(Bv, l - 8);
    float4 Bp  = shfl4(Bv, l + 8);
    float sAm = __shfl(mA, l - 8), sAp = __shfl(mA, l + 8), sA56 = __shfl(mA, l + 56);
    float sBm = __shfl(mB, l - 8), sBp = __shfl(mB, l + 8), sB56 = __shfl(mB, l - 56);

    const bool lo = (l < 8), hi = (l >= 56);
    float4 prevA = sel4(lo, kv, Am);
    float4 nextA = sel4(hi, AfB, Apl);
    float4 prevB = sel4(lo, BfA, Bm);
    float4 nextB = sel4(hi, make_float4(0.f, 0.f, 0.f, 0.f), Bp);
    float pmA = lo ? 1.f : sAm;
    float nmA = hi ? sB56 : sAp;
    float pmB = lo ? sA56 : sBm;
    float nmB = hi ? 0.f : sBp;

    float4 nA, nB;
    nA.x = ap * prevA.x + apop * nextA.x + an * A.x;
    nA.y = ap * prevA.y + apop * nextA.y + an * A.y;
    nA.z = ap * prevA.z + apop * nextA.z + an * A.z;
    nA.w = ap * prevA.w + apop * nextA.w + an * A.w;
    nB.x = ap * prevB.x + apop * nextB.x + an * Bv.x;
    nB.y = ap * prevB.y + apop * nextB.y + an * Bv.y;
    nB.z = ap * prevB.z + apop * nextB.z + an * Bv.z;
    nB.w = ap * prevB.w + apop * nextB.w + an * Bv.w;
    float nmaskA = ap * pmA + apop * nmA + an * mA;
    float nmaskB = ap * pmB + apop * nmB + an * mB;

    // store new_stack: two 1 KB coalesced stores + mask
    float* ostack = out + OUT_STACK_OFF + (size_t)tok * 8192 + nh * 512;
    float4* ost4 = (float4*)ostack;
    ost4[l] = nA;
    ost4[64 + l] = nB;
    if ((l & 7) == 0) {
        float* om = out + OUT_MASK_OFF + (size_t)tok * 256 + nh * 16;
        om[l >> 3] = nmaskA;
        om[8 + (l >> 3)] = nmaskB;
    }

    // gate scores: dot over d (reduce quarters: xor 1/2/4 within slot group)
    float gA = dot4(nA, wg);
    float gB = dot4(nB, wg);
    #pragma unroll
    for (int off = 1; off <= 4; off <<= 1) {
        gA += __shfl_xor(gA, off);
        gB += __shfl_xor(gB, off);
    }
    float bgv = bgp[0];
    gA += bgv + (1.f - nmaskA) * -1e9f;
    gB += bgv + (1.f - nmaskB) * -1e9f;

    // softmax over 16 slots (xor 8/16/32 spans all slot groups)
    float gm = fmaxf(gA, gB);
    #pragma unroll
    for (int off = 8; off <= 32; off <<= 1) gm = fmaxf(gm, __shfl_xor(gm, off));
    float eA = __expf(gA - gm), eB = __expf(gB - gm);
    float es = eA + eB;
    #pragma unroll
    for (int off = 8; off <= 32; off <<= 1) es += __shfl_xor(es, off);
    float ginv = 1.f / es;
    float gateA = eA * ginv, gateB = eB * ginv;

    // mem: butterfly over slot groups -> EVERY lane ends with the full sum
    // for its quarter q = l&7 (components 0..3 = dims q*4 .. q*4+3)
    float4 sv;
    sv.x = gateA * nA.x + gateB * nB.x;
    sv.y = gateA * nA.y + gateB * nB.y;
    sv.z = gateA * nA.z + gateB * nB.z;
    sv.w = gateA * nA.w + gateB * nB.w;
    #pragma unroll
    for (int off = 8; off <= 32; off <<= 1) {
        sv.x += __shfl_xor(sv.x, off);
        sv.y += __shfl_xor(sv.y, off);
        sv.z += __shfl_xor(sv.z, off);
        sv.w += __shfl_xor(sv.w, off);
    }

    // ---- out = mem @ Wu + bu, * res_weight + hidden; lane -> element l ----
    // mem[q*4+c] lives in lane q (q<8 holds quarter q): 8 broadcast shuffles.
    float acc = bu[l];
    #pragma unroll
    for (int q = 0; q < 8; ++q) {
        float4 mq = shfl4(sv, q);                    // uniform-src broadcast
        acc += mq.x * Wu[(q * 4 + 0) * 64 + l]
             + mq.y * Wu[(q * 4 + 1) * 64 + l]
             + mq.z * Wu[(q * 4 + 2) * 64 + l]
             + mq.w * Wu[(q * 4 + 3) * 64 + l];      // 256 B coalesced, L1-hot
    }
    size_t oidx = (size_t)tok * 1024 + nh * 64 + l;
    out[oidx] = acc * resw[0] + sh_hid[nh * 64 + l];
}

extern "C" void kernel_launch(void* const* d_in, const int* in_sizes, int n_in,
                              void* d_out, int out_size, void* d_ws, size_t ws_size,
                              hipStream_t stream) {
    const float* hid  = (const float*)d_in[0];
    const float* stk  = (const float*)d_in[1];
    const float* msk  = (const float*)d_in[2];
    const float* Wa   = (const float*)d_in[3];
    const float* ba   = (const float*)d_in[4];
    const float* Wd   = (const float*)d_in[5];
    const float* bd   = (const float*)d_in[6];
    const float* Wu   = (const float*)d_in[7];
    const float* bu   = (const float*)d_in[8];
    const float* Wg   = (const float*)d_in[9];
    const float* bg   = (const float*)d_in[10];
    const float* rw   = (const float*)d_in[11];
    float* out = (float*)d_out;
    float* waT = (float*)d_ws;   // 48*1024 floats = 192 KiB scratch

    transpose_wa<<<192, 256, 0, stream>>>(Wa, waT);
    stack_main<<<32768, 256, 0, stream>>>(hid, stk, msk, waT, ba, Wd, bd,
                                          Wg, bg, Wu, bu, rw, out);
}

// Round 5
// 601.245 us; speedup vs baseline: 1.0860x; 1.0860x over previous
//
#include <hip/hip_runtime.h>

// StackMemory pipeline for MI355X (gfx950).
// B=4, S=2048, H=1024, NH=16, SLOTS=16, SD=32, HD=64. 8192 tokens.
//
// Two-kernel structure (fusion measured SLOWER: 285us fused vs ~208us split,
// latency-bound chain):
//   proj_kernel : action logits (raw, scaled) + k projection for all tokens,
//                 stashed into the new_stack OUTPUT region (slot0 = k,
//                 slot1[0:3] = logits). Each (tok,head) slice is read then
//                 fully overwritten by the SAME wave in stack_main.
//   stack_main  : TWO (token,head) units per wave (ILP for latency hiding).
//                 Lane l <-> float4 (slot=l>>3, q=l&7); 1KB coalesced global
//                 loads/stores; slot shift via shuffles; xor-32 reduce stages
//                 via v_permlane32_swap (VALU pipe, not DS) where available;
//                 epilogue via ds_read_b128 broadcast (9 DS ops/unit).
//
// Outputs concatenated flat: out [8192*1024] | new_stack [8192*8192] | new_mask [8192*256]

constexpr long long OUT_STACK_OFF = 8388608LL;     // 4*2048*1024
constexpr long long OUT_MASK_OFF  = 75497472LL;    // + 4*2048*16*16*32

__global__ void transpose_wa(const float* __restrict__ Wa, float* __restrict__ WaT) {
    int o = blockIdx.x * 256 + threadIdx.x;        // 48*1024 elements
    if (o < 48 * 1024) {
        int j = o >> 10, i = o & 1023;
        WaT[o] = Wa[i * 48 + j];
    }
}

__device__ __forceinline__ float dot4(float4 a, float4 b) {
    return a.x * b.x + a.y * b.y + a.z * b.z + a.w * b.w;
}

__device__ __forceinline__ float4 shfl4(float4 v, int src) {
    return make_float4(__shfl(v.x, src), __shfl(v.y, src),
                       __shfl(v.z, src), __shfl(v.w, src));
}

__device__ __forceinline__ float4 sel4(bool c, float4 a, float4 b) {
    return make_float4(c ? a.x : b.x, c ? a.y : b.y, c ? a.z : b.z, c ? a.w : b.w);
}

// xor-32 reduce stage on the VALU pipe (v_permlane32_swap) when available.
#if defined(__has_builtin) && __has_builtin(__builtin_amdgcn_permlane32_swap)
typedef int v2i_t __attribute__((ext_vector_type(2)));
__device__ __forceinline__ float red32_add(float x) {
    v2i_t r = __builtin_amdgcn_permlane32_swap(__float_as_int(x), __float_as_int(x),
                                               false, false);
    return __int_as_float(r.x) + __int_as_float(r.y);
}
__device__ __forceinline__ float red32_max(float x) {
    v2i_t r = __builtin_amdgcn_permlane32_swap(__float_as_int(x), __float_as_int(x),
                                               false, false);
    return fmaxf(__int_as_float(r.x), __int_as_float(r.y));
}
#else
__device__ __forceinline__ float red32_add(float x) { return x + __shfl_xor(x, 32); }
__device__ __forceinline__ float red32_max(float x) { return fmaxf(x, __shfl_xor(x, 32)); }
#endif

// ---------------------------------------------------------------------------
// Phase 1: raw scaled logits + k projection, 4 tokens per block (amortizes
// the 192 KB WaT read 4x). No LDS -> high residency.  (verbatim R1 pass)
// ---------------------------------------------------------------------------
__global__ __launch_bounds__(256)
void proj_kernel(const float* __restrict__ hid,
                 const float* __restrict__ WaT,   // [48][1024]
                 const float* __restrict__ ba,    // [48]
                 const float* __restrict__ Wd,    // [64][32]
                 const float* __restrict__ bd,    // [32]
                 float* __restrict__ out)
{
    const int t = threadIdx.x;
    const int wv = t >> 6, lane = t & 63;
    const int tok0 = blockIdx.x * 4;
    float* stash = out + OUT_STACK_OFF;
    const float4* hid4 = (const float4*)hid + (size_t)tok0 * 256;

    float4 hreg[4][4];
    #pragma unroll
    for (int tt = 0; tt < 4; ++tt)
        #pragma unroll
        for (int m = 0; m < 4; ++m)
            hreg[tt][m] = hid4[tt * 256 + m * 64 + lane];

    // ---- logits: wave wv computes j in [12wv, 12wv+12) for all 4 tokens ----
    const float4* waT4 = (const float4*)WaT;
    #pragma unroll
    for (int jj = 0; jj < 12; ++jj) {
        int j = wv * 12 + jj;
        float a0 = 0.f, a1 = 0.f, a2 = 0.f, a3 = 0.f;
        #pragma unroll
        for (int m = 0; m < 4; ++m) {
            float4 w = waT4[j * 256 + m * 64 + lane];
            a0 += dot4(hreg[0][m], w);
            a1 += dot4(hreg[1][m], w);
            a2 += dot4(hreg[2][m], w);
            a3 += dot4(hreg[3][m], w);
        }
        #pragma unroll
        for (int off = 1; off <= 16; off <<= 1) {
            a0 += __shfl_xor(a0, off);
            a1 += __shfl_xor(a1, off);
            a2 += __shfl_xor(a2, off);
            a3 += __shfl_xor(a3, off);
        }
        a0 = red32_add(a0); a1 = red32_add(a1); a2 = red32_add(a2); a3 = red32_add(a3);
        if ((lane & 15) == jj) {                 // lanes jj, jj+16, jj+32, jj+48
            int tt = lane >> 4;
            float v = (tt == 0) ? a0 : (tt == 1) ? a1 : (tt == 2) ? a2 : a3;
            int nh = wv * 4 + jj / 3, a = jj - 3 * (jj / 3);
            stash[(size_t)(tok0 + tt) * 8192 + nh * 512 + 32 + a] = (v + ba[j]) * 0.125f;
        }
    }

    // ---- k projection: thread -> dim d = t&31, heads nhg and nhg+8, 4 tokens ----
    const int d = t & 31, nhg = t >> 5;
    float acc0[4], acc1[4];
    float bdv = bd[d];
    #pragma unroll
    for (int tt = 0; tt < 4; ++tt) { acc0[tt] = bdv; acc1[tt] = bdv; }
    #pragma unroll
    for (int ii = 0; ii < 16; ++ii) {
        float w0 = Wd[(4 * ii + 0) * 32 + d];
        float w1 = Wd[(4 * ii + 1) * 32 + d];
        float w2 = Wd[(4 * ii + 2) * 32 + d];
        float w3 = Wd[(4 * ii + 3) * 32 + d];
        #pragma unroll
        for (int tt = 0; tt < 4; ++tt) {
            float4 ha = hid4[tt * 256 + nhg * 16 + ii];        // broadcast, L1-hot
            float4 hb = hid4[tt * 256 + (nhg + 8) * 16 + ii];
            acc0[tt] += ha.x * w0 + ha.y * w1 + ha.z * w2 + ha.w * w3;
            acc1[tt] += hb.x * w0 + hb.y * w1 + hb.z * w2 + hb.w * w3;
        }
    }
    #pragma unroll
    for (int tt = 0; tt < 4; ++tt) {
        stash[(size_t)(tok0 + tt) * 8192 + nhg * 512 + d] = acc0[tt];
        stash[(size_t)(tok0 + tt) * 8192 + (nhg + 8) * 512 + d] = acc1[tt];
    }
}

// ---------------------------------------------------------------------------
// Phase 2: TWO (token,head) units per wave. Lane l <-> float4 (slot=l>>3, q=l&7).
// Block = 4 waves = 8 units = half a token's heads. Unit u of wave wv:
//   tok = bid>>1, nh = (bid&1)*8 + wv + 4*u.
// ---------------------------------------------------------------------------
__global__ __launch_bounds__(256, 4)
void stack_main(const float* __restrict__ stack,
                const float* __restrict__ mask,
                const float* __restrict__ hid,
                const float* __restrict__ Wg,    // [32]
                const float* __restrict__ bgp,   // [1]
                const float* __restrict__ Wu,    // [32][64]
                const float* __restrict__ bu,    // [64]
                const float* __restrict__ resw,  // [1]
                float* __restrict__ out)
{
    __shared__ __align__(16) float sh_mem[4][2][32];
    const int t = threadIdx.x, wv = t >> 6, l = t & 63;
    const int bid = blockIdx.x;
    const int tok = bid >> 1;
    const int nhb = ((bid & 1) << 3) + wv;        // nh of unit 0; unit 1 = +4

    const float4* stkt = (const float4*)stack + (size_t)tok * 2048;
    float* ostack_base = out + OUT_STACK_OFF + (size_t)tok * 8192;
    const float* mrow_g = mask + (size_t)tok * 256;

    // ---- issue ALL global loads for both units up front ----
    float4 A[2], Bv[2], kv[2], lgv[2];
    float mA[2], mB[2];
    #pragma unroll
    for (int u = 0; u < 2; ++u) {
        const int nh = nhb + 4 * u;
        const float4* stk4 = stkt + nh * 128;
        A[u]  = stk4[l];                          // slots 0..7 (1 KB coalesced)
        Bv[u] = stk4[64 + l];                     // slots 8..15
        const float4* stash4 = (const float4*)(ostack_base + nh * 512);
        kv[u]  = stash4[l & 7];                   // k quarter (stash, ours to overwrite)
        lgv[u] = stash4[8];                       // raw logits in .x .y .z
        mA[u] = mrow_g[nh * 16 + (l >> 3)];
        mB[u] = mrow_g[nh * 16 + 8 + (l >> 3)];
    }
    const float4 wg = *(const float4*)(Wg + (l & 7) * 4);
    const float bgv = bgp[0];
    const bool lo = (l < 8), hi = (l >= 56);

    // ---- action softmax (VALU only, wave-uniform per unit) ----
    float ap[2], apop[2], an[2];
    #pragma unroll
    for (int u = 0; u < 2; ++u) {
        float mx = fmaxf(lgv[u].x, fmaxf(lgv[u].y, lgv[u].z));
        float e0 = __expf(lgv[u].x - mx), e1 = __expf(lgv[u].y - mx), e2 = __expf(lgv[u].z - mx);
        float ainv = 1.f / (e0 + e1 + e2);
        ap[u] = e0 * ainv; apop[u] = e1 * ainv; an[u] = e2 * ainv;
    }

    // ---- stack update + stores (both units interleaved by unroll) ----
    float4 nA[2], nB[2];
    float nmaskA[2], nmaskB[2];
    #pragma unroll
    for (int u = 0; u < 2; ++u) {
        float4 Am  = shfl4(A[u],  l - 8);
        float4 Apl = shfl4(A[u],  l + 8);
        float4 BfA = shfl4(A[u],  l + 56);   // slot7 -> prev of slot8 (lanes l<8)
        float4 AfB = shfl4(Bv[u], l - 56);   // slot8 -> next of slot7 (lanes l>=56)
        float4 Bm  = shfl4(Bv[u], l - 8);
        float4 Bp  = shfl4(Bv[u], l + 8);
        float sAm = __shfl(mA[u], l - 8), sAp = __shfl(mA[u], l + 8), sA56 = __shfl(mA[u], l + 56);
        float sBm = __shfl(mB[u], l - 8), sBp = __shfl(mB[u], l + 8), sB56 = __shfl(mB[u], l - 56);

        float4 prevA = sel4(lo, kv[u], Am);
        float4 nextA = sel4(hi, AfB, Apl);
        float4 prevB = sel4(lo, BfA, Bm);
        float4 nextB = sel4(hi, make_float4(0.f, 0.f, 0.f, 0.f), Bp);
        float pmA = lo ? 1.f : sAm;
        float nmA = hi ? sB56 : sAp;
        float pmB = lo ? sA56 : sBm;
        float nmB = hi ? 0.f : sBp;

        nA[u].x = ap[u] * prevA.x + apop[u] * nextA.x + an[u] * A[u].x;
        nA[u].y = ap[u] * prevA.y + apop[u] * nextA.y + an[u] * A[u].y;
        nA[u].z = ap[u] * prevA.z + apop[u] * nextA.z + an[u] * A[u].z;
        nA[u].w = ap[u] * prevA.w + apop[u] * nextA.w + an[u] * A[u].w;
        nB[u].x = ap[u] * prevB.x + apop[u] * nextB.x + an[u] * Bv[u].x;
        nB[u].y = ap[u] * prevB.y + apop[u] * nextB.y + an[u] * Bv[u].y;
        nB[u].z = ap[u] * prevB.z + apop[u] * nextB.z + an[u] * Bv[u].z;
        nB[u].w = ap[u] * prevB.w + apop[u] * nextB.w + an[u] * Bv[u].w;
        nmaskA[u] = ap[u] * pmA + apop[u] * nmA + an[u] * mA[u];
        nmaskB[u] = ap[u] * pmB + apop[u] * nmB + an[u] * mB[u];

        const int nh = nhb + 4 * u;
        float4* ost4 = (float4*)(ostack_base + nh * 512);
        ost4[l] = nA[u];
        ost4[64 + l] = nB[u];
        if ((l & 7) == 0) {
            float* om = out + OUT_MASK_OFF + (size_t)tok * 256 + nh * 16;
            om[l >> 3] = nmaskA[u];
            om[8 + (l >> 3)] = nmaskB[u];
        }
    }

    // ---- gate softmax + mem reduce (xor-32 stages on VALU via permlane) ----
    #pragma unroll
    for (int u = 0; u < 2; ++u) {
        float gA = dot4(nA[u], wg);
        float gB = dot4(nB[u], wg);
        #pragma unroll
        for (int off = 1; off <= 4; off <<= 1) {
            gA += __shfl_xor(gA, off);
            gB += __shfl_xor(gB, off);
        }
        gA += bgv + (1.f - nmaskA[u]) * -1e9f;
        gB += bgv + (1.f - nmaskB[u]) * -1e9f;

        float gm = fmaxf(gA, gB);
        gm = fmaxf(gm, __shfl_xor(gm, 8));
        gm = fmaxf(gm, __shfl_xor(gm, 16));
        gm = red32_max(gm);
        float eA = __expf(gA - gm), eB = __expf(gB - gm);
        float es = eA + eB;
        es += __shfl_xor(es, 8);
        es += __shfl_xor(es, 16);
        es = red32_add(es);
        float ginv = 1.f / es;
        float gateA = eA * ginv, gateB = eB * ginv;

        float4 sv;
        sv.x = gateA * nA[u].x + gateB * nB[u].x;
        sv.y = gateA * nA[u].y + gateB * nB[u].y;
        sv.z = gateA * nA[u].z + gateB * nB[u].z;
        sv.w = gateA * nA[u].w + gateB * nB[u].w;
        #pragma unroll
        for (int off = 8; off <= 16; off <<= 1) {
            sv.x += __shfl_xor(sv.x, off);
            sv.y += __shfl_xor(sv.y, off);
            sv.z += __shfl_xor(sv.z, off);
            sv.w += __shfl_xor(sv.w, off);
        }
        sv.x = red32_add(sv.x);
        sv.y = red32_add(sv.y);
        sv.z = red32_add(sv.z);
        sv.w = red32_add(sv.w);
        if (l < 8) *(float4*)&sh_mem[wv][u][l * 4] = sv;   // mem quarter l
    }
    __syncthreads();

    // ---- out = mem @ Wu + bu, * res_weight + hidden; lane -> element l ----
    const float rw = resw[0];
    const float buv = bu[l];
    #pragma unroll
    for (int u = 0; u < 2; ++u) {
        float acc = buv;
        const float4* m4 = (const float4*)sh_mem[wv][u];
        #pragma unroll
        for (int q = 0; q < 8; ++q) {
            float4 mq = m4[q];                    // uniform-address LDS broadcast
            acc += mq.x * Wu[(q * 4 + 0) * 64 + l]
                 + mq.y * Wu[(q * 4 + 1) * 64 + l]
                 + mq.z * Wu[(q * 4 + 2) * 64 + l]
                 + mq.w * Wu[(q * 4 + 3) * 64 + l];
        }
        const int nh = nhb + 4 * u;
        size_t oidx = (size_t)tok * 1024 + nh * 64 + l;
        out[oidx] = acc * rw + hid[oidx];
    }
}

extern "C" void kernel_launch(void* const* d_in, const int* in_sizes, int n_in,
                              void* d_out, int out_size, void* d_ws, size_t ws_size,
                              hipStream_t stream) {
    const float* hid  = (const float*)d_in[0];
    const float* stk  = (const float*)d_in[1];
    const float* msk  = (const float*)d_in[2];
    const float* Wa   = (const float*)d_in[3];
    const float* ba   = (const float*)d_in[4];
    const float* Wd   = (const float*)d_in[5];
    const float* bd   = (const float*)d_in[6];
    const float* Wu   = (const float*)d_in[7];
    const float* bu   = (const float*)d_in[8];
    const float* Wg   = (const float*)d_in[9];
    const float* bg   = (const float*)d_in[10];
    const float* rw   = (const float*)d_in[11];
    float* out = (float*)d_out;
    float* waT = (float*)d_ws;   // 48*1024 floats = 192 KiB scratch

    transpose_wa<<<192, 256, 0, stream>>>(Wa, waT);
    proj_kernel<<<2048, 256, 0, stream>>>(hid, waT, ba, Wd, bd, out);
    stack_main<<<16384, 256, 0, stream>>>(stk, msk, hid, Wg, bg, Wu, bu, rw, out);
}